// Round 2
// 118.245 us; speedup vs baseline: 1.0204x; 1.0204x over previous
//
#include <hip/hip_runtime.h>
#include <math.h>

#define Bn 8
#define Hn 256
#define Wn 256
#define HW (Hn * Wn)
#define ROWS 8
#define RP 264  // padded row length (words); data at [4..259], zeros at 3/260
#define ZW (20 * RP)  // zero region: rowsF[ZW .. ZW+63] == 0

typedef __attribute__((ext_vector_type(8))) short bf16x8;
typedef __attribute__((ext_vector_type(4))) float f32x4;
typedef __attribute__((ext_vector_type(2))) float f32x2;

// Pack two fp32 (raw bits) into packed bf16x2 by truncation: one v_perm.
__device__ __forceinline__ unsigned int pk_bits(unsigned int lo,
                                                unsigned int hi) {
  return __builtin_amdgcn_perm(hi, lo, 0x07060302u);
}
__device__ __forceinline__ unsigned int pk_bf16(float lo, float hi) {
  return pk_bits(__float_as_uint(lo), __float_as_uint(hi));
}

// k-slot -> tap mapping (tap = pl*9 + rr*3 + dx), chosen so that on every
// gather instruction q0 and q1 hit DISJOINT 16-bank halves:
//   pairs (pl,rr=0,dx)<->(pl,rr=2,dx): addr delta 2*RP=528 == 16 (mod 32)
//   pairs (pl0,rr=1,dx)<->(pl1,rr=1,dx): delta 10*RP=2640 == 16 (mod 32)
__device__ __constant__ const int T0c[8] = {0, 1, 2, 9, 10, 11, 3, 4};
__device__ __constant__ const int T1c[8] = {6, 7, 8, 15, 16, 17, 12, 13};
__device__ __constant__ const int T2c[8] = {5, 14, -1, -1, -1, -1, -1, -1};

// Kernel A (R11, resubmit): fused conv1(2->64,3x3)+ReLU -> conv2(64->1) ->
// sigmoid -> gate. R11 vs R10 (120.7 us total):
//  - conv2 epilogue: packed-f32 (v_pk_max/v_pk_fma) with 4 parallel partial
//    sums; dependency depth 16 -> 4, VALU instr count -32/row
//  - base plane no longer copied into comb (mix reads it from x)
//  - gather bases advanced incrementally (addr += step), no per-row mul
__global__ __launch_bounds__(256) void sim_kernel(
    const float* __restrict__ x,   // (8,7,256,256)
    const float* __restrict__ W1,  // (6,64,2,3,3)
    const float* __restrict__ b1,  // (6,64)
    const float* __restrict__ W2,  // (6,1,64,1,1)
    const float* __restrict__ b2,  // (6,1)
    float* __restrict__ comb)      // (8,7,256,256)
{
  __shared__ float rowsF[20 * RP + 64];  // 21.4 KB rows + zero region
  __shared__ uint4 wq[4][64];            // 4 KB A-frags

  int bi = blockIdx.x;
  int n  = bi >> 8;            // 0..5
  int b  = (bi >> 5) & 7;      // 0..7
  int h0 = (bi & 31) * ROWS;   // chunk start row
  int cc = (n < 3) ? n : n + 1;
  int t = threadIdx.x;

  const float* xb     = x + (size_t)b * 7 * HW;
  const float* basep  = xb + 3 * HW;
  const float* checkp = xb + (size_t)cc * HW;

  // ---- stage weights in MFMA A-layout with the k-remap ----
  {
    int f = t >> 6, qq = (t >> 4) & 3, m = t & 15;
    int bsrc = (n < 3) ? 0 : 1;  // weight input-ch that multiplies BASE
    const float* wch = W1 + ((size_t)(n * 64 + 16 * f + m)) * 18;
    unsigned int kv[4];
#pragma unroll
    for (int jj = 0; jj < 4; ++jj) {
      int ja = 2 * jj, jb = 2 * jj + 1;
      int ta = (qq == 0) ? T0c[ja] : (qq == 1) ? T1c[ja]
               : (qq == 2) ? T2c[ja] : -1;
      int tb = (qq == 0) ? T0c[jb] : (qq == 1) ? T1c[jb]
               : (qq == 2) ? T2c[jb] : -1;
      float va = 0.f, vb = 0.f;
      if (ta >= 0) {
        int pl = ta / 9, rem = ta - pl * 9;
        va = wch[(pl ? 1 - bsrc : bsrc) * 9 + rem];
      }
      if (tb >= 0) {
        int pl = tb / 9, rem = tb - pl * 9;
        vb = wch[(pl ? 1 - bsrc : bsrc) * 9 + rem];
      }
      kv[jj] = pk_bf16(va, vb);
    }
    wq[f][(qq << 4) + m] = make_uint4(kv[0], kv[1], kv[2], kv[3]);
  }

  // ---- per-lane conv2/bias params (global loads, no LDS dep) ----
  int lane = t & 63, wvid = t >> 6;
  int q = lane >> 4, m_ = lane & 15;
  f32x2 w2A[4], w2B[4];
  f32x4 b1vv[4];
#pragma unroll
  for (int f = 0; f < 4; ++f) {
    float4 tw = *(const float4*)&W2[n * 64 + 16 * f + 4 * q];
    float4 tb = *(const float4*)&b1[n * 64 + 16 * f + 4 * q];
    w2A[f][0] = tw.x; w2A[f][1] = tw.y;
    w2B[f][0] = tw.z; w2B[f][1] = tw.w;
    b1vv[f][0] = tb.x; b1vv[f][1] = tb.y;
    b1vv[f][2] = tb.z; b1vv[f][3] = tb.w;
  }
  float bb = b2[n];

  // ---- stage raw rows: 20 rows x 256 cols -> rowsF[rf*RP + 4 + col] ----
  {
    int col = (t & 63) << 2;
#pragma unroll
    for (int it = 0; it < 5; ++it) {
      int rf = it * 4 + (t >> 6);  // 0..19 = pl*10 + j
      int pl = (rf >= 10) ? 1 : 0;
      int j  = rf - pl * 10;
      int hh = h0 - 1 + j;
      const float* src = pl ? checkp : basep;
      float4 val = make_float4(0.f, 0.f, 0.f, 0.f);
      if ((unsigned)hh < (unsigned)Hn)
        val = *(const float4*)(src + hh * Wn + col);
      *(float4*)&rowsF[rf * RP + 4 + col] = val;
    }
    if (t < 20) {  // edge zeros
      rowsF[t * RP + 3] = 0.f;
      rowsF[t * RP + 260] = 0.f;
    }
    if (t >= 192) rowsF[ZW + (t - 192)] = 0.f;  // zero region (64 words)
  }

  // ---- per-lane gather table: slot jh (k = 8q + jh) ----
  const unsigned int* rowsU = (const unsigned int*)rowsF;
  unsigned int addr[8], step[8];
#pragma unroll
  for (int jh = 0; jh < 8; ++jh) {
    int tap = (q == 0) ? T0c[jh] : (q == 1) ? T1c[jh]
              : (q == 2) ? T2c[jh] : -1;
    if (tap >= 0) {
      int pl = tap / 9, rem = tap - pl * 9;
      int rr = rem / 3, dx = rem - rr * 3;
      addr[jh] = (pl * 10 + rr) * RP + 3 + dx + wvid * 64 + m_;
      step[jh] = (unsigned)RP;
    } else {
      addr[jh] = (unsigned)ZW;  // zero region; +16/32/48 also zero
      step[jh] = 0u;
    }
  }

  __syncthreads();

  // A fragments (contiguous 16 B per lane, conflict-free)
  bf16x8 afrag[4];
#pragma unroll
  for (int f = 0; f < 4; ++f) afrag[f] = *(const bf16x8*)&wq[f][lane];

  float* combcc = comb + ((size_t)b * 7 + cc) * HW;
  int pxs = wvid * 64 + lane;

#pragma unroll 1
  for (int r = 0; r < ROWS; ++r) {
    int h = h0 + r;

    float g[4];
#pragma unroll
    for (int half = 0; half < 2; ++half) {
      // gather strip pair (2*half, 2*half+1): one vaddr, imm offsets
      // {32*half, 32*half+16} words -> ds_read2_b32
      unsigned int dlo[8], dhi[8];
#pragma unroll
      for (int jh = 0; jh < 8; ++jh) {
        dlo[jh] = rowsU[addr[jh] + half * 32];
        dhi[jh] = rowsU[addr[jh] + half * 32 + 16];
      }
#pragma unroll
      for (int j = 0; j < 2; ++j) {
        const unsigned int* d = j ? dhi : dlo;
        union { unsigned int u[4]; bf16x8 v; } bu;
#pragma unroll
        for (int jj = 0; jj < 4; ++jj)
          bu.u[jj] = pk_bits(d[2 * jj], d[2 * jj + 1]);

        f32x4 acc[4];
#pragma unroll
        for (int f = 0; f < 4; ++f)
          acc[f] = __builtin_amdgcn_mfma_f32_16x16x32_bf16(afrag[f], bu.v,
                                                           b1vv[f], 0, 0, 0);

        // conv2: packed relu+dot, 4 parallel partials (2 f32x2 lanes)
        f32x2 sA = {0.f, 0.f}, sB = {0.f, 0.f};
#pragma unroll
        for (int f = 0; f < 4; ++f) {
          f32x2 a01, a23;
          a01[0] = acc[f][0]; a01[1] = acc[f][1];
          a23[0] = acc[f][2]; a23[1] = acc[f][3];
          a01 = __builtin_elementwise_max(a01, (f32x2)0.f);
          a23 = __builtin_elementwise_max(a23, (f32x2)0.f);
          sA += w2A[f] * a01;  // fp-contract -> v_pk_fma_f32
          sB += w2B[f] * a23;
        }
        float sp = (sA[0] + sB[0]) + (sA[1] + sB[1]);
        sp += __shfl_xor(sp, 16, 64);
        sp += __shfl_xor(sp, 32, 64);
        sp += bb;

        float e = __builtin_amdgcn_exp2f(sp * -1.442695041f);
        g[2 * half + j] = __builtin_amdgcn_rcpf(1.f + e);
      }
    }

    // Coalesced store: lane l -> px = wvid*64 + l, gate g[l>>4]
    int hi = lane >> 4;
    float gsel = (hi == 0) ? g[0] : (hi == 1) ? g[1] : (hi == 2) ? g[2] : g[3];
    float ccv = rowsF[(10 + r + 1) * RP + 4 + pxs];  // check center
    combcc[h * Wn + pxs] = gsel * ccv;

#pragma unroll
    for (int jh = 0; jh < 8; ++jh) addr[jh] += step[jh];
  }
}

// Kernel B (R11, resubmit): final mixing conv (7->7, 3x3, SAME), LDS-staged.
// Block = (b, 4-row chunk) -> 512 blocks, 512 threads (2 blocks/CU,
// 16 waves/CU). LDS = 7 planes x 6 rows x RP = 44.4 KB. Halo overhead
// 6/4 vs 4/2 -> comb reads 29.4 -> 22 MB. Base plane (ic==3) is read
// directly from x (sim no longer copies it into comb).
__global__ __launch_bounds__(512) void mix_kernel(
    const float* __restrict__ comb,  // (8,7,256,256), plane 3 unused
    const float* __restrict__ x,     // (8,7,256,256), plane 3 = base
    const float* __restrict__ Wm,    // (7,7,3,3)
    const float* __restrict__ bm,    // (7,)
    float* __restrict__ out)         // (8,7,256,256)
{
  __shared__ float mr[42 * RP];  // 44.4 KB

  int bi = blockIdx.x;           // 0..511
  int b  = bi >> 6;
  int h0 = (bi & 63) << 2;
  int t = threadIdx.x;

  // stage: 42 rows (ic*6 + j) x 64 float4
  for (int u = t; u < 42 * 64; u += 512) {
    int rf = u >> 6;             // 0..41 = ic*6 + j
    int col = (u & 63) << 2;
    int ic = rf / 6, j = rf - ic * 6;
    int hh = h0 - 1 + j;
    const float* src = (ic == 3) ? (x + ((size_t)b * 7 + 3) * HW)
                                 : (comb + ((size_t)b * 7 + ic) * HW);
    float4 v = make_float4(0.f, 0.f, 0.f, 0.f);
    if ((unsigned)hh < (unsigned)Hn)
      v = *(const float4*)(src + hh * Wn + col);
    *(float4*)&mr[rf * RP + 4 + col] = v;
  }
  if (t < 42) {
    mr[t * RP + 3] = 0.f;
    mr[t * RP + 260] = 0.f;
  }
  __syncthreads();

  int r   = t >> 7;           // local row 0..3
  int px0 = (t & 127) << 1;   // 0..254
  int h   = h0 + r;

  float acc[7][2];
#pragma unroll
  for (int oc = 0; oc < 7; ++oc) {
    float bv = bm[oc];
    acc[oc][0] = bv;
    acc[oc][1] = bv;
  }

#pragma unroll 1
  for (int ic = 0; ic < 7; ++ic) {
    float w[3][4];
#pragma unroll
    for (int dy = 0; dy < 3; ++dy) {
      const float* rp = &mr[(ic * 6 + r + dy) * RP + 3 + px0];
      w[dy][0] = rp[0]; w[dy][1] = rp[1];  // adjacent -> ds_read2
      w[dy][2] = rp[2]; w[dy][3] = rp[3];
    }
    const float* wp = Wm + ic * 9;
#pragma unroll
    for (int oc = 0; oc < 7; ++oc) {
      const float* wo = wp + oc * 63;
#pragma unroll
      for (int dy = 0; dy < 3; ++dy)
#pragma unroll
        for (int dx = 0; dx < 3; ++dx) {
          float wvv = wo[dy * 3 + dx];
          acc[oc][0] = fmaf(wvv, w[dy][0 + dx], acc[oc][0]);
          acc[oc][1] = fmaf(wvv, w[dy][1 + dx], acc[oc][1]);
        }
    }
  }

  float* ob = out + (size_t)b * 7 * HW + h * Wn + px0;
#pragma unroll
  for (int oc = 0; oc < 7; ++oc)
    *(float2*)(ob + (size_t)oc * HW) = make_float2(acc[oc][0], acc[oc][1]);
}

extern "C" void kernel_launch(void* const* d_in, const int* in_sizes, int n_in,
                              void* d_out, int out_size, void* d_ws, size_t ws_size,
                              hipStream_t stream) {
  const float* x  = (const float*)d_in[0];
  const float* W1 = (const float*)d_in[1];
  const float* b1 = (const float*)d_in[2];
  const float* W2 = (const float*)d_in[3];
  const float* b2 = (const float*)d_in[4];
  const float* Wm = (const float*)d_in[5];
  const float* bm = (const float*)d_in[6];
  float* out  = (float*)d_out;
  float* comb = (float*)d_ws;  // 8*7*256*256 floats = 14.7 MB

  sim_kernel<<<6 * 8 * (Hn / ROWS), 256, 0, stream>>>(x, W1, b1, W2, b2, comb);
  mix_kernel<<<8 * (Hn / 4), 512, 0, stream>>>(comb, x, Wm, bm, out);
}

// Round 3
// 116.485 us; speedup vs baseline: 1.0358x; 1.0151x over previous
//
#include <hip/hip_runtime.h>
#include <math.h>

#define Bn 8
#define Hn 256
#define Wn 256
#define HW (Hn * Wn)
#define ROWS 8
#define RP 264  // padded row length (words); data at [4..259], zeros at 3/260
#define ZW (20 * RP)  // zero region: rowsF[ZW .. ZW+63] == 0

typedef __attribute__((ext_vector_type(8))) short bf16x8;
typedef __attribute__((ext_vector_type(4))) float f32x4;
typedef __attribute__((ext_vector_type(2))) float f32x2;

// Pack two fp32 (raw bits) into packed bf16x2 by truncation: one v_perm.
__device__ __forceinline__ unsigned int pk_bits(unsigned int lo,
                                                unsigned int hi) {
  return __builtin_amdgcn_perm(hi, lo, 0x07060302u);
}
__device__ __forceinline__ unsigned int pk_bf16(float lo, float hi) {
  return pk_bits(__float_as_uint(lo), __float_as_uint(hi));
}

// k-slot -> tap mapping (tap = pl*9 + rr*3 + dx), chosen so that on every
// gather instruction q0 and q1 hit DISJOINT 16-bank halves:
//   pairs (pl,rr=0,dx)<->(pl,rr=2,dx): addr delta 2*RP=528 == 16 (mod 32)
//   pairs (pl0,rr=1,dx)<->(pl1,rr=1,dx): delta 10*RP=2640 == 16 (mod 32)
__device__ __constant__ const int T0c[8] = {0, 1, 2, 9, 10, 11, 3, 4};
__device__ __constant__ const int T1c[8] = {6, 7, 8, 15, 16, 17, 12, 13};
__device__ __constant__ const int T2c[8] = {5, 14, -1, -1, -1, -1, -1, -1};

// Kernel A (R12): fused conv1(2->64,3x3)+ReLU -> conv2(64->1) -> sigmoid ->
// gate. R12 vs R11 (sim 43.5 us, MfmaUtil 11%, VALUBusy 62%, conflicts ~0):
// R10/R11 VALU cuts were Δ≈0 -> NOT VALU-throughput-bound; latency-bound on
// the serial per-row chain (gather -> pack -> MFMA -> dot -> 2x LDS shuffle
// -> exp -> rcp) with unroll(1) serializing rows. This round:
//  - half-row software pipeline, 2 register buffers: gather(h1) issued
//    before compute(h0), gather(next row h0) before compute(h1)
//  - both gates of a half computed together (2x ILP on the epilogue chain)
//  - xor16 reduce via immediate ds_swizzle 0x401F; xor32 via ds_bpermute
//    with precomputed (lane^32)*4 address
//  - step[8] -> two per-lane scalars (jh<2 / jh>=2)
__global__ __launch_bounds__(256, 4) void sim_kernel(
    const float* __restrict__ x,   // (8,7,256,256)
    const float* __restrict__ W1,  // (6,64,2,3,3)
    const float* __restrict__ b1,  // (6,64)
    const float* __restrict__ W2,  // (6,1,64,1,1)
    const float* __restrict__ b2,  // (6,1)
    float* __restrict__ comb)      // (8,7,256,256)
{
  __shared__ float rowsF[20 * RP + 64];  // 21.4 KB rows + zero region
  __shared__ uint4 wq[4][64];            // 4 KB A-frags

  int bi = blockIdx.x;
  int n  = bi >> 8;            // 0..5
  int b  = (bi >> 5) & 7;      // 0..7
  int h0 = (bi & 31) * ROWS;   // chunk start row
  int cc = (n < 3) ? n : n + 1;
  int t = threadIdx.x;

  const float* xb     = x + (size_t)b * 7 * HW;
  const float* basep  = xb + 3 * HW;
  const float* checkp = xb + (size_t)cc * HW;

  // ---- stage weights in MFMA A-layout with the k-remap ----
  {
    int f = t >> 6, qq = (t >> 4) & 3, m = t & 15;
    int bsrc = (n < 3) ? 0 : 1;  // weight input-ch that multiplies BASE
    const float* wch = W1 + ((size_t)(n * 64 + 16 * f + m)) * 18;
    unsigned int kv[4];
#pragma unroll
    for (int jj = 0; jj < 4; ++jj) {
      int ja = 2 * jj, jb = 2 * jj + 1;
      int ta = (qq == 0) ? T0c[ja] : (qq == 1) ? T1c[ja]
               : (qq == 2) ? T2c[ja] : -1;
      int tb = (qq == 0) ? T0c[jb] : (qq == 1) ? T1c[jb]
               : (qq == 2) ? T2c[jb] : -1;
      float va = 0.f, vb = 0.f;
      if (ta >= 0) {
        int pl = ta / 9, rem = ta - pl * 9;
        va = wch[(pl ? 1 - bsrc : bsrc) * 9 + rem];
      }
      if (tb >= 0) {
        int pl = tb / 9, rem = tb - pl * 9;
        vb = wch[(pl ? 1 - bsrc : bsrc) * 9 + rem];
      }
      kv[jj] = pk_bf16(va, vb);
    }
    wq[f][(qq << 4) + m] = make_uint4(kv[0], kv[1], kv[2], kv[3]);
  }

  // ---- per-lane conv2/bias params (global loads, no LDS dep) ----
  int lane = t & 63, wvid = t >> 6;
  int q = lane >> 4, m_ = lane & 15;
  f32x2 w2A[4], w2B[4];
  f32x4 b1vv[4];
#pragma unroll
  for (int f = 0; f < 4; ++f) {
    float4 tw = *(const float4*)&W2[n * 64 + 16 * f + 4 * q];
    float4 tb = *(const float4*)&b1[n * 64 + 16 * f + 4 * q];
    w2A[f][0] = tw.x; w2A[f][1] = tw.y;
    w2B[f][0] = tw.z; w2B[f][1] = tw.w;
    b1vv[f][0] = tb.x; b1vv[f][1] = tb.y;
    b1vv[f][2] = tb.z; b1vv[f][3] = tb.w;
  }
  float bb = b2[n];

  // ---- stage raw rows: 20 rows x 256 cols -> rowsF[rf*RP + 4 + col] ----
  {
    int col = (t & 63) << 2;
#pragma unroll
    for (int it = 0; it < 5; ++it) {
      int rf = it * 4 + (t >> 6);  // 0..19 = pl*10 + j
      int pl = (rf >= 10) ? 1 : 0;
      int j  = rf - pl * 10;
      int hh = h0 - 1 + j;
      const float* src = pl ? checkp : basep;
      float4 val = make_float4(0.f, 0.f, 0.f, 0.f);
      if ((unsigned)hh < (unsigned)Hn)
        val = *(const float4*)(src + hh * Wn + col);
      *(float4*)&rowsF[rf * RP + 4 + col] = val;
    }
    if (t < 20) {  // edge zeros
      rowsF[t * RP + 3] = 0.f;
      rowsF[t * RP + 260] = 0.f;
    }
    if (t >= 192) rowsF[ZW + (t - 192)] = 0.f;  // zero region (64 words)
  }

  // ---- per-lane gather table: slot jh (k = 8q + jh) ----
  const unsigned int* rowsU = (const unsigned int*)rowsF;
  unsigned int addr[8];
#pragma unroll
  for (int jh = 0; jh < 8; ++jh) {
    int tap = (q == 0) ? T0c[jh] : (q == 1) ? T1c[jh]
              : (q == 2) ? T2c[jh] : -1;
    if (tap >= 0) {
      int pl = tap / 9, rem = tap - pl * 9;
      int rr = rem / 3, dx = rem - rr * 3;
      addr[jh] = (pl * 10 + rr) * RP + 3 + dx + wvid * 64 + m_;
    } else {
      addr[jh] = (unsigned)ZW;  // zero region; +16/32/48 also zero
    }
  }
  // per-lane row steps: jh<2 real iff q<=2, jh>=2 real iff q<2 (dead
  // slots stay frozen on the zero region)
  unsigned int stepA = (q <= 2) ? (unsigned)RP : 0u;
  unsigned int stepB = (q < 2) ? (unsigned)RP : 0u;
  int bpaddr = ((lane ^ 32) << 2);  // ds_bpermute byte address for xor32

  __syncthreads();

  // A fragments (contiguous 16 B per lane, conflict-free)
  bf16x8 afrag[4];
#pragma unroll
  for (int f = 0; f < 4; ++f) afrag[f] = *(const bf16x8*)&wq[f][lane];

  float* combcc = comb + ((size_t)b * 7 + cc) * HW;
  int pxs = wvid * 64 + lane;

  // Both gates of one half: pack 8, 8 MFMA, dual epilogue (2x ILP on the
  // reduce/exp chain).
  auto compute2 = [&](const unsigned int* dbuf, float& gA, float& gB) {
    union { unsigned int u[4]; bf16x8 v; } p0, p1;
#pragma unroll
    for (int jj = 0; jj < 4; ++jj) {
      p0.u[jj] = pk_bits(dbuf[2 * jj], dbuf[2 * jj + 1]);
      p1.u[jj] = pk_bits(dbuf[8 + 2 * jj], dbuf[8 + 2 * jj + 1]);
    }
    f32x4 acc0[4], acc1[4];
#pragma unroll
    for (int f = 0; f < 4; ++f) {
      acc0[f] = __builtin_amdgcn_mfma_f32_16x16x32_bf16(afrag[f], p0.v,
                                                        b1vv[f], 0, 0, 0);
      acc1[f] = __builtin_amdgcn_mfma_f32_16x16x32_bf16(afrag[f], p1.v,
                                                        b1vv[f], 0, 0, 0);
    }
    f32x2 sA0 = {0.f, 0.f}, sB0 = {0.f, 0.f};
    f32x2 sA1 = {0.f, 0.f}, sB1 = {0.f, 0.f};
#pragma unroll
    for (int f = 0; f < 4; ++f) {
      f32x2 a01, a23, c01, c23;
      a01[0] = acc0[f][0]; a01[1] = acc0[f][1];
      a23[0] = acc0[f][2]; a23[1] = acc0[f][3];
      c01[0] = acc1[f][0]; c01[1] = acc1[f][1];
      c23[0] = acc1[f][2]; c23[1] = acc1[f][3];
      a01 = __builtin_elementwise_max(a01, (f32x2)0.f);
      a23 = __builtin_elementwise_max(a23, (f32x2)0.f);
      c01 = __builtin_elementwise_max(c01, (f32x2)0.f);
      c23 = __builtin_elementwise_max(c23, (f32x2)0.f);
      sA0 += w2A[f] * a01;
      sB0 += w2B[f] * a23;
      sA1 += w2A[f] * c01;
      sB1 += w2B[f] * c23;
    }
    float sp0 = (sA0[0] + sB0[0]) + (sA0[1] + sB0[1]);
    float sp1 = (sA1[0] + sB1[0]) + (sA1[1] + sB1[1]);
    // xor16 via immediate ds_swizzle (no addr setup), both gates in parallel
    sp0 += __int_as_float(
        __builtin_amdgcn_ds_swizzle(__float_as_int(sp0), 0x401F));
    sp1 += __int_as_float(
        __builtin_amdgcn_ds_swizzle(__float_as_int(sp1), 0x401F));
    // xor32 via ds_bpermute with precomputed address
    sp0 += __int_as_float(
        __builtin_amdgcn_ds_bpermute(bpaddr, __float_as_int(sp0)));
    sp1 += __int_as_float(
        __builtin_amdgcn_ds_bpermute(bpaddr, __float_as_int(sp1)));
    sp0 += bb;
    sp1 += bb;
    float e0 = __builtin_amdgcn_exp2f(sp0 * -1.442695041f);
    float e1 = __builtin_amdgcn_exp2f(sp1 * -1.442695041f);
    gA = __builtin_amdgcn_rcpf(1.f + e0);
    gB = __builtin_amdgcn_rcpf(1.f + e1);
  };

  // ---- software-pipelined row loop (half-row granularity) ----
  unsigned int bufA[16], bufB[16];
  // prologue: gather (row 0, half 0), strips {0,1} -> word offsets {0,16}
#pragma unroll
  for (int jh = 0; jh < 8; ++jh) {
    bufA[jh]     = rowsU[addr[jh]];
    bufA[jh + 8] = rowsU[addr[jh] + 16];
  }

#pragma unroll 1
  for (int r = 0; r < ROWS; ++r) {
    float ccv = rowsF[(10 + r + 1) * RP + 4 + pxs];  // check center (early)

    // prefetch half 1 (strips {2,3} -> word offsets {32,48})
#pragma unroll
    for (int jh = 0; jh < 8; ++jh) {
      bufB[jh]     = rowsU[addr[jh] + 32];
      bufB[jh + 8] = rowsU[addr[jh] + 48];
    }

    float g0, g1, g2, g3;
    compute2(bufA, g0, g1);  // hides bufB gather latency

    if (r < ROWS - 1) {  // advance + prefetch next row half 0
#pragma unroll
      for (int jh = 0; jh < 8; ++jh) {
        addr[jh] += (jh < 2) ? stepA : stepB;
        bufA[jh]     = rowsU[addr[jh]];
        bufA[jh + 8] = rowsU[addr[jh] + 16];
      }
    }

    compute2(bufB, g2, g3);  // hides bufA gather latency

    // Coalesced store: lane l -> px = wvid*64 + l, gate g[l>>4]
    int hi = lane >> 4;
    float gsel = (hi == 0) ? g0 : (hi == 1) ? g1 : (hi == 2) ? g2 : g3;
    combcc[(h0 + r) * Wn + pxs] = gsel * ccv;
  }
}

// Kernel B (R11, unchanged): final mixing conv (7->7, 3x3, SAME), LDS-staged.
// Block = (b, 4-row chunk) -> 512 blocks, 512 threads (2 blocks/CU,
// 16 waves/CU). LDS = 7 planes x 6 rows x RP = 44.4 KB. Base plane (ic==3)
// is read directly from x (sim does not copy it into comb).
__global__ __launch_bounds__(512) void mix_kernel(
    const float* __restrict__ comb,  // (8,7,256,256), plane 3 unused
    const float* __restrict__ x,     // (8,7,256,256), plane 3 = base
    const float* __restrict__ Wm,    // (7,7,3,3)
    const float* __restrict__ bm,    // (7,)
    float* __restrict__ out)         // (8,7,256,256)
{
  __shared__ float mr[42 * RP];  // 44.4 KB

  int bi = blockIdx.x;           // 0..511
  int b  = bi >> 6;
  int h0 = (bi & 63) << 2;
  int t = threadIdx.x;

  // stage: 42 rows (ic*6 + j) x 64 float4
  for (int u = t; u < 42 * 64; u += 512) {
    int rf = u >> 6;             // 0..41 = ic*6 + j
    int col = (u & 63) << 2;
    int ic = rf / 6, j = rf - ic * 6;
    int hh = h0 - 1 + j;
    const float* src = (ic == 3) ? (x + ((size_t)b * 7 + 3) * HW)
                                 : (comb + ((size_t)b * 7 + ic) * HW);
    float4 v = make_float4(0.f, 0.f, 0.f, 0.f);
    if ((unsigned)hh < (unsigned)Hn)
      v = *(const float4*)(src + hh * Wn + col);
    *(float4*)&mr[rf * RP + 4 + col] = v;
  }
  if (t < 42) {
    mr[t * RP + 3] = 0.f;
    mr[t * RP + 260] = 0.f;
  }
  __syncthreads();

  int r   = t >> 7;           // local row 0..3
  int px0 = (t & 127) << 1;   // 0..254
  int h   = h0 + r;

  float acc[7][2];
#pragma unroll
  for (int oc = 0; oc < 7; ++oc) {
    float bv = bm[oc];
    acc[oc][0] = bv;
    acc[oc][1] = bv;
  }

#pragma unroll 1
  for (int ic = 0; ic < 7; ++ic) {
    float w[3][4];
#pragma unroll
    for (int dy = 0; dy < 3; ++dy) {
      const float* rp = &mr[(ic * 6 + r + dy) * RP + 3 + px0];
      w[dy][0] = rp[0]; w[dy][1] = rp[1];  // adjacent -> ds_read2
      w[dy][2] = rp[2]; w[dy][3] = rp[3];
    }
    const float* wp = Wm + ic * 9;
#pragma unroll
    for (int oc = 0; oc < 7; ++oc) {
      const float* wo = wp + oc * 63;
#pragma unroll
      for (int dy = 0; dy < 3; ++dy)
#pragma unroll
        for (int dx = 0; dx < 3; ++dx) {
          float wvv = wo[dy * 3 + dx];
          acc[oc][0] = fmaf(wvv, w[dy][0 + dx], acc[oc][0]);
          acc[oc][1] = fmaf(wvv, w[dy][1 + dx], acc[oc][1]);
        }
    }
  }

  float* ob = out + (size_t)b * 7 * HW + h * Wn + px0;
#pragma unroll
  for (int oc = 0; oc < 7; ++oc)
    *(float2*)(ob + (size_t)oc * HW) = make_float2(acc[oc][0], acc[oc][1]);
}

extern "C" void kernel_launch(void* const* d_in, const int* in_sizes, int n_in,
                              void* d_out, int out_size, void* d_ws, size_t ws_size,
                              hipStream_t stream) {
  const float* x  = (const float*)d_in[0];
  const float* W1 = (const float*)d_in[1];
  const float* b1 = (const float*)d_in[2];
  const float* W2 = (const float*)d_in[3];
  const float* b2 = (const float*)d_in[4];
  const float* Wm = (const float*)d_in[5];
  const float* bm = (const float*)d_in[6];
  float* out  = (float*)d_out;
  float* comb = (float*)d_ws;  // 8*7*256*256 floats = 14.7 MB

  sim_kernel<<<6 * 8 * (Hn / ROWS), 256, 0, stream>>>(x, W1, b1, W2, b2, comb);
  mix_kernel<<<8 * (Hn / 4), 512, 0, stream>>>(comb, x, Wm, bm, out);
}